// Round 1
// baseline (79.523 us; speedup 1.0000x reference)
//
#include <hip/hip_runtime.h>
#include <math.h>

// Quanv3x3: B=4, H=W=32, CIN=3, COUT=4, NQ=9 qubits, 8 CRZ+CRX gate pairs.
// One 64-lane wave simulates one (patch, cout) circuit.
// Amplitude index n (9 bits, qubit0 = MSB): lane carries qubits 0..5
// (q0->lane bit5 ... q5->lane bit0), register r in [0,8) carries qubits 6..8
// (q6->r bit2, q7->r bit1, q8->r bit0).

namespace {
constexpr int kB = 4, kH = 32, kW = 32, kCIN = 3, kCOUT = 4;
constexpr int kFX = 30, kFY = 30;
constexpr float kPI = 3.14159265358979323846f;
}

// Controlled-RZ, ctrl & tgt both lane bits. RZ is diagonal: amp *= (cz, +/-sz)
#define CRZ_LL(CMASK, TMASK, K) do {                                          \
    const float cz = gc[K], sz = gs[K];                                       \
    const bool ctl = (lane & (CMASK)) != 0;                                   \
    const float ce = ctl ? cz : 1.0f;                                         \
    const float se = ctl ? (((lane & (TMASK)) != 0) ? sz : -sz) : 0.0f;       \
    _Pragma("unroll")                                                         \
    for (int r = 0; r < 8; ++r) {                                             \
        const float nre = ce * re[r] - se * im[r];                            \
        const float nim = ce * im[r] + se * re[r];                            \
        re[r] = nre; im[r] = nim;                                             \
    }                                                                         \
} while (0)

// Controlled-RX, ctrl & tgt both lane bits. Pair across tgt bit via shfl_xor.
// new = cx*self + sx*(partner.im, -partner.re)   [since RX off-diag = -i*sx]
#define CRX_LL(CMASK, TMASK, K) do {                                          \
    const float cx = gc[K], sx = gs[K];                                       \
    const bool ctl = (lane & (CMASK)) != 0;                                   \
    _Pragma("unroll")                                                         \
    for (int r = 0; r < 8; ++r) {                                             \
        const float pre = __shfl_xor(re[r], (TMASK), 64);                     \
        const float pim = __shfl_xor(im[r], (TMASK), 64);                     \
        const float nre = cx * re[r] + sx * pim;                              \
        const float nim = cx * im[r] - sx * pre;                              \
        re[r] = ctl ? nre : re[r];                                            \
        im[r] = ctl ? nim : im[r];                                            \
    }                                                                         \
} while (0)

__global__ __launch_bounds__(256) void quanv9q_kernel(
    const float* __restrict__ x, const float* __restrict__ qp,
    float* __restrict__ out)
{
    const int lane = threadIdx.x & 63;
    const int wave = (blockIdx.x * blockDim.x + threadIdx.x) >> 6;
    if (wave >= kB * kFX * kFY * kCOUT) return;

    const int co  = wave & 3;
    const int p   = wave >> 2;
    const int b   = p / (kFX * kFY);
    const int rem = p - b * (kFX * kFY);
    const int pi  = rem / kFY;
    const int pj  = rem - pi * kFY;

    // ---- setup: lanes 0..8 compute patch half-angle trig, lanes 0..15 gate trig
    float myc = 0.f, mys = 0.f, mgc = 1.f, mgs = 0.f;
    if (lane < 9) {
        const int di = lane / 3, dj = lane % 3;
        const float* px = x + (((b * kH + (pi + di)) * kW + (pj + dj)) * kCIN);
        const float v = (px[0] + px[1] + px[2]) * (1.0f / 3.0f);
        // amps use 0.5*(2*pi*v - pi) = pi*v - pi/2
        const float half = kPI * v - 0.5f * kPI;
        myc = cosf(half); mys = sinf(half);
    }
    if (lane < 16) {
        const float th = 0.5f * qp[co * 16 + lane];
        mgc = cosf(th); mgs = sinf(th);
    }
    float cq[9], sq[9];
    #pragma unroll
    for (int q = 0; q < 9; ++q) { cq[q] = __shfl(myc, q, 64); sq[q] = __shfl(mys, q, 64); }
    float gc[16], gs[16];
    #pragma unroll
    for (int k = 0; k < 16; ++k) { gc[k] = __shfl(mgc, k, 64); gs[k] = __shfl(mgs, k, 64); }

    // ---- initial product state: amp = (prod mags) * (-i)^popcount(bits)
    float plane_m = 1.0f;
    #pragma unroll
    for (int q = 0; q < 6; ++q)
        plane_m *= ((lane >> (5 - q)) & 1) ? sq[q] : cq[q];
    const int pcl = __popc(lane);

    float re[8], im[8];
    #pragma unroll
    for (int r = 0; r < 8; ++r) {
        const int b6 = (r >> 2) & 1, b7 = (r >> 1) & 1, b8 = r & 1;
        float m = plane_m;
        m *= b6 ? sq[6] : cq[6];
        m *= b7 ? sq[7] : cq[7];
        m *= b8 ? sq[8] : cq[8];
        const int pc = (pcl + b6 + b7 + b8) & 3;   // (-i)^pc
        re[r] = (pc == 0) ? m : ((pc == 2) ? -m : 0.0f);
        im[r] = (pc == 1) ? -m : ((pc == 3) ? m : 0.0f);
    }

    // ---- gates: (ctrl,tgt,k) = (1,0,0)(3,2,2)(2,0,4)(8,7,6)(5,4,8)(7,6,10)(6,4,12)(4,0,14)
    CRZ_LL(16, 32, 0);  CRX_LL(16, 32, 1);   // (1,0): ctrl lane b4, tgt lane b5
    CRZ_LL(4, 8, 2);    CRX_LL(4, 8, 3);     // (3,2): ctrl lane b2, tgt lane b3
    CRZ_LL(8, 32, 4);   CRX_LL(8, 32, 5);    // (2,0): ctrl lane b3, tgt lane b5

    // (8,7): ctrl r bit0, tgt r bit1 — in-register
    {
        const float cz = gc[6], sz = gs[6];
        #pragma unroll
        for (int r = 1; r < 8; r += 2) {              // ctrl (q8) set
            const float se = (r & 2) ? sz : -sz;      // tgt (q7) bit
            const float nre = cz * re[r] - se * im[r];
            const float nim = cz * im[r] + se * re[r];
            re[r] = nre; im[r] = nim;
        }
        const float cx = gc[7], sx = gs[7];
        #pragma unroll
        for (int base = 0; base < 8; base += 4) {     // pairs (1,3),(5,7)
            const int a = base + 1, c2 = base + 3;
            const float are = re[a], aim = im[a], bre = re[c2], bim = im[c2];
            re[a]  = cx * are + sx * bim;  im[a]  = cx * aim - sx * bre;
            re[c2] = cx * bre + sx * aim;  im[c2] = cx * bim - sx * are;
        }
    }

    CRZ_LL(1, 2, 8);    CRX_LL(1, 2, 9);     // (5,4): ctrl lane b0, tgt lane b1

    // (7,6): ctrl r bit1, tgt r bit2 — in-register
    {
        const float cz = gc[10], sz = gs[10];
        #pragma unroll
        for (int r = 0; r < 8; ++r) if (r & 2) {      // ctrl (q7) set
            const float se = (r & 4) ? sz : -sz;      // tgt (q6) bit
            const float nre = cz * re[r] - se * im[r];
            const float nim = cz * im[r] + se * re[r];
            re[r] = nre; im[r] = nim;
        }
        const float cx = gc[11], sx = gs[11];
        #pragma unroll
        for (int a0 = 2; a0 <= 3; ++a0) {             // pairs (2,6),(3,7)
            const int a = a0, c2 = a0 + 4;
            const float are = re[a], aim = im[a], bre = re[c2], bim = im[c2];
            re[a]  = cx * are + sx * bim;  im[a]  = cx * aim - sx * bre;
            re[c2] = cx * bre + sx * aim;  im[c2] = cx * bim - sx * are;
        }
    }

    // (6,4): ctrl r bit2, tgt lane bit1 — mixed
    {
        const float cz = gc[12], sz = gs[12];
        const float se = ((lane & 2) != 0) ? sz : -sz;
        #pragma unroll
        for (int r = 4; r < 8; ++r) {                 // ctrl (q6) set
            const float nre = cz * re[r] - se * im[r];
            const float nim = cz * im[r] + se * re[r];
            re[r] = nre; im[r] = nim;
        }
        const float cx = gc[13], sx = gs[13];
        #pragma unroll
        for (int r = 4; r < 8; ++r) {
            const float pre = __shfl_xor(re[r], 2, 64);
            const float pim = __shfl_xor(im[r], 2, 64);
            const float nre = cx * re[r] + sx * pim;
            const float nim = cx * im[r] - sx * pre;
            re[r] = nre; im[r] = nim;
        }
    }

    CRZ_LL(2, 32, 14);  CRX_LL(2, 32, 15);   // (4,0): ctrl lane b1, tgt lane b5

    // ---- p0 = sum |amp|^2 over qubit0 == 0 (lanes 0..31)
    float ssum = 0.0f;
    if ((lane & 32) == 0) {
        #pragma unroll
        for (int r = 0; r < 8; ++r) ssum += re[r] * re[r] + im[r] * im[r];
    }
    #pragma unroll
    for (int off = 32; off > 0; off >>= 1) ssum += __shfl_xor(ssum, off, 64);

    if (lane == 0)
        out[((b * kH + (pi + 1)) * kW + (pj + 1)) * kCOUT + co] = ssum;
}

extern "C" void kernel_launch(void* const* d_in, const int* in_sizes, int n_in,
                              void* d_out, int out_size, void* d_ws, size_t ws_size,
                              hipStream_t stream) {
    const float* x  = (const float*)d_in[0];   // (4,32,32,3) f32
    const float* qp = (const float*)d_in[1];   // (4,16) f32
    float* out = (float*)d_out;                // (4,32,32,4) f32

    // borders stay zero; interior written by kernel
    hipMemsetAsync(d_out, 0, (size_t)out_size * sizeof(float), stream);

    const int total_waves = kB * kFX * kFY * kCOUT;   // 14400
    const int threads = 256;                          // 4 waves / block
    const int blocks = (total_waves * 64 + threads - 1) / threads;  // 3600
    quanv9q_kernel<<<blocks, threads, 0, stream>>>(x, qp, out);
}

// Round 2
// 73.803 us; speedup vs baseline: 1.0775x; 1.0775x over previous
//
#include <hip/hip_runtime.h>
#include <math.h>

// Quanv3x3 9-qubit circuit sim. One 64-lane wave per (patch, cout).
//
// Phase gauge: conjugate the whole circuit by D = ⊗_q diag(1, i).
//  - init product state becomes PURELY REAL: amp(n) = prod_q (bit? sin : cos)
//  - CRZ unchanged (diagonal commutes with diagonal)
//  - CRX becomes controlled REAL rotation [[c,-s],[s,c]] (no re/im mixing)
//  - measured |amp|^2 unchanged (D is diagonal unitary)
//
// Qubit -> storage map (chosen so CRX targets are register bits where possible):
//  register r (3 bits): bit2 = q0, bit1 = q2, bit0 = q4
//  lane (6 bits):       b0 = q7, b1 = q6, b2 = q8, b3 = q5, b4 = q3, b5 = q1
// Gates (ctrl,tgt,k): (1,0)(3,2)(2,0)(8,7)(5,4)(7,6)(6,4)(4,0)
//  -> 6 gates have register targets (pure in-register pair rotation),
//     2 gates (tgt q7,q6) use DPP quad_perm xor1 / xor2 (VALU pipe, no LDS).

namespace {
constexpr int kB = 4, kH = 32, kW = 32, kCIN = 3, kCOUT = 4;
constexpr int kFX = 30, kFY = 30;
constexpr float kPI = 3.14159265358979323846f;
}

template <int CTRL>
__device__ __forceinline__ float dpp_perm(float v) {
    return __int_as_float(
        __builtin_amdgcn_mov_dpp(__float_as_int(v), CTRL, 0xF, 0xF, true));
}
__device__ __forceinline__ float rdlane(float v, int l) {
    return __int_as_float(__builtin_amdgcn_readlane(__float_as_int(v), l));
}

// ---- gate macros (operate on re[8], im[8]) ------------------------------
// CRZ, lane ctrl (mask CB), register target bit TBIT.
// tgt=0: amp *= (cz - i sz)  -> re' = cz re + sz im ; im' = cz im - sz re
// tgt=1: conj.
#define CRZ_LR(CB, TBIT, K) do {                                           \
    const bool ctl = (lane & (CB)) != 0;                                   \
    const float ce = ctl ? gc[K] : 1.0f;                                   \
    const float se = ctl ? gs[K] : 0.0f;                                   \
    _Pragma("unroll")                                                      \
    for (int r = 0; r < 8; ++r) {                                          \
        const float sg = (r & (TBIT)) ? -se : se;                          \
        const float nr = ce * re[r] + sg * im[r];                          \
        const float ni = ce * im[r] - sg * re[r];                          \
        re[r] = nr; im[r] = ni;                                            \
    }                                                                      \
} while (0)

// CRX (real rotation), lane ctrl, register target bit: a'=c a - s b; b'=s a + c b
#define CRX_LR(CB, TBIT, K) do {                                           \
    const bool ctl = (lane & (CB)) != 0;                                   \
    const float ce = ctl ? gc[K] : 1.0f;                                   \
    const float se = ctl ? gs[K] : 0.0f;                                   \
    _Pragma("unroll")                                                      \
    for (int r = 0; r < 8; ++r) if (!(r & (TBIT))) {                       \
        const int r2 = r | (TBIT);                                         \
        const float ar = re[r], ai = im[r], br = re[r2], bi = im[r2];      \
        re[r]  = ce * ar - se * br;  im[r]  = ce * ai - se * bi;           \
        re[r2] = se * ar + ce * br;  im[r2] = se * ai + ce * bi;           \
    }                                                                      \
} while (0)

// CRZ, register ctrl bit CBIT, register target bit TBIT (no lane masking)
#define CRZ_RR(CBIT, TBIT, K) do {                                         \
    const float ce = gc[K], se = gs[K];                                    \
    _Pragma("unroll")                                                      \
    for (int r = 0; r < 8; ++r) if (r & (CBIT)) {                          \
        const float sg = (r & (TBIT)) ? -se : se;                          \
        const float nr = ce * re[r] + sg * im[r];                          \
        const float ni = ce * im[r] - sg * re[r];                          \
        re[r] = nr; im[r] = ni;                                            \
    }                                                                      \
} while (0)

// CRX, register ctrl bit, register target bit
#define CRX_RR(CBIT, TBIT, K) do {                                         \
    const float ce = gc[K], se = gs[K];                                    \
    _Pragma("unroll")                                                      \
    for (int r = 0; r < 8; ++r) if ((r & (CBIT)) && !(r & (TBIT))) {       \
        const int r2 = r | (TBIT);                                         \
        const float ar = re[r], ai = im[r], br = re[r2], bi = im[r2];      \
        re[r]  = ce * ar - se * br;  im[r]  = ce * ai - se * bi;           \
        re[r2] = se * ar + ce * br;  im[r2] = se * ai + ce * bi;           \
    }                                                                      \
} while (0)

// CRZ, lane ctrl, lane target bit TB
#define CRZ_LL(CB, TB, K) do {                                             \
    const bool ctl = (lane & (CB)) != 0;                                   \
    const float ce  = ctl ? gc[K] : 1.0f;                                  \
    const float se0 = ctl ? gs[K] : 0.0f;                                  \
    const float se  = (lane & (TB)) ? -se0 : se0;                          \
    _Pragma("unroll")                                                      \
    for (int r = 0; r < 8; ++r) {                                          \
        const float nr = ce * re[r] + se * im[r];                          \
        const float ni = ce * im[r] - se * re[r];                          \
        re[r] = nr; im[r] = ni;                                            \
    }                                                                      \
} while (0)

// CRX, lane ctrl, lane target bit TB (partner via DPP quad_perm, VALU pipe).
// self tgt=0: new = c*self - s*partner ; tgt=1: new = c*self + s*partner
#define CRX_LL_DPP(CB, TB, DPPC, K) do {                                   \
    const bool ctl = (lane & (CB)) != 0;                                   \
    const float ce  = ctl ? gc[K] : 1.0f;                                  \
    const float se0 = ctl ? gs[K] : 0.0f;                                  \
    const float se  = (lane & (TB)) ? se0 : -se0;                          \
    _Pragma("unroll")                                                      \
    for (int r = 0; r < 8; ++r) {                                          \
        const float pr  = dpp_perm<DPPC>(re[r]);                           \
        const float pim = dpp_perm<DPPC>(im[r]);                           \
        re[r] = ce * re[r] + se * pr;                                      \
        im[r] = ce * im[r] + se * pim;                                     \
    }                                                                      \
} while (0)

__global__ __launch_bounds__(256) void quanv9q_kernel(
    const float* __restrict__ x, const float* __restrict__ qp,
    float* __restrict__ out)
{
    const int lane = threadIdx.x & 63;
    const int wave = (blockIdx.x << 2) + (threadIdx.x >> 6);

    const int co  = wave & 3;
    const int p   = wave >> 2;
    const int b   = p / (kFX * kFY);
    const int rem = p - b * (kFX * kFY);
    const int oy  = rem / kFY;
    const int ox  = rem - oy * kFY;

    // ---- trig: lanes 0..8 patch half-angles, lanes 0..15 gate half-angles
    float myc = 0.f, mys = 0.f, mgc = 0.f, mgs = 0.f;
    if (lane < 9) {
        const int di = lane / 3, dj = lane - (lane / 3) * 3;
        const float* px = x + (((b * kH + (oy + di)) * kW + (ox + dj)) * kCIN);
        const float v = (px[0] + px[1] + px[2]) * (1.0f / 3.0f);
        sincosf(kPI * v - 0.5f * kPI, &mys, &myc);   // half-angle of 2*pi*v - pi
    }
    if (lane < 16) {
        sincosf(0.5f * qp[co * 16 + lane], &mgs, &mgc);
    }
    // patch trig -> uniform VGPRs (DS pipe, overlaps); gate trig -> SGPRs
    float cq[9], sq[9];
    #pragma unroll
    for (int q = 0; q < 9; ++q) { cq[q] = __shfl(myc, q, 64); sq[q] = __shfl(mys, q, 64); }
    float gc[16], gs[16];
    #pragma unroll
    for (int k = 0; k < 16; ++k) { gc[k] = rdlane(mgc, k); gs[k] = rdlane(mgs, k); }

    // ---- real initial product state
    float pm = 1.0f;
    pm *= (lane & 1)  ? sq[7] : cq[7];
    pm *= (lane & 2)  ? sq[6] : cq[6];
    pm *= (lane & 4)  ? sq[8] : cq[8];
    pm *= (lane & 8)  ? sq[5] : cq[5];
    pm *= (lane & 16) ? sq[3] : cq[3];
    pm *= (lane & 32) ? sq[1] : cq[1];

    float re[8], im[8];
    {
        const float a0 = pm * cq[0], a1 = pm * sq[0];                 // q0 (bit2)
        const float b00 = a0 * cq[2], b01 = a0 * sq[2];               // q2 (bit1)
        const float b10 = a1 * cq[2], b11 = a1 * sq[2];
        re[0] = b00 * cq[4]; re[1] = b00 * sq[4];                     // q4 (bit0)
        re[2] = b01 * cq[4]; re[3] = b01 * sq[4];
        re[4] = b10 * cq[4]; re[5] = b10 * sq[4];
        re[6] = b11 * cq[4]; re[7] = b11 * sq[4];
    }
    #pragma unroll
    for (int r = 0; r < 8; ++r) im[r] = 0.0f;

    // ---- gates (ctrl,tgt,k): lane masks: q1=32 q3=16 q5=8 q8=4 q6=2 q7=1
    CRZ_LR(32, 4, 0);   CRX_LR(32, 4, 1);          // (1,0)
    CRZ_LR(16, 2, 2);   CRX_LR(16, 2, 3);          // (3,2)
    CRZ_RR(2, 4, 4);    CRX_RR(2, 4, 5);           // (2,0)
    CRZ_LL(4, 1, 6);    CRX_LL_DPP(4, 1, 0xB1, 7); // (8,7) xor1 = quad_perm[1,0,3,2]
    CRZ_LR(8, 1, 8);    CRX_LR(8, 1, 9);           // (5,4)
    CRZ_LL(1, 2, 10);   CRX_LL_DPP(1, 2, 0x4E, 11);// (7,6) xor2 = quad_perm[2,3,0,1]
    CRZ_LR(2, 1, 12);   CRX_LR(2, 1, 13);          // (6,4)
    CRZ_RR(1, 4, 14);   CRX_RR(1, 4, 15);          // (4,0)

    // ---- p0 = sum |amp|^2 over q0=0 (regs 0..3), all lanes
    float ssum = 0.0f;
    #pragma unroll
    for (int r = 0; r < 4; ++r) ssum += re[r] * re[r] + im[r] * im[r];
    #pragma unroll
    for (int off = 32; off > 0; off >>= 1) ssum += __shfl_xor(ssum, off, 64);

    if (lane == 0)
        out[((b * kH + (oy + 1)) * kW + (ox + 1)) * kCOUT + co] = ssum;
}

extern "C" void kernel_launch(void* const* d_in, const int* in_sizes, int n_in,
                              void* d_out, int out_size, void* d_ws, size_t ws_size,
                              hipStream_t stream) {
    const float* x  = (const float*)d_in[0];   // (4,32,32,3) f32
    const float* qp = (const float*)d_in[1];   // (4,16) f32
    float* out = (float*)d_out;                // (4,32,32,4) f32

    hipMemsetAsync(d_out, 0, (size_t)out_size * sizeof(float), stream);

    const int total_waves = kB * kFX * kFY * kCOUT;                 // 14400
    const int threads = 256;                                        // 4 waves/block
    const int blocks = total_waves * 64 / threads;                  // 3600 exact
    quanv9q_kernel<<<blocks, threads, 0, stream>>>(x, qp, out);
}

// Round 3
// 71.748 us; speedup vs baseline: 1.1084x; 1.0286x over previous
//
#include <hip/hip_runtime.h>
#include <math.h>

// Quanv3x3 9-qubit circuit sim. One 64-lane wave per (patch, cout).
//
// Phase gauge: conjugate the whole circuit by D = ⊗_q diag(1, i).
//  - init product state becomes PURELY REAL
//  - CRZ unchanged (diagonal), CRX becomes controlled REAL rotation
//  - measured |amp|^2 unchanged
//
// Qubit -> storage map:
//  register r (3 bits): bit2 = q0, bit1 = q2, bit0 = q4
//  lane (6 bits):       b0 = q7, b1 = q6, b2 = q8, b3 = q5, b4 = q3, b5 = q1
// Gates (ctrl,tgt): (1,0)(3,2)(2,0)(8,7)(5,4)(7,6)(6,4)(4,0)
//  -> 6 gates have register targets (in-register pair rotation),
//     2 gates (tgt q7,q6) use DPP quad_perm xor1/xor2 (VALU pipe, no LDS).
//
// Trig: hardware v_sin/v_cos in REVOLUTIONS — all angles bounded in
// [-0.25, 0.25] rev so no range reduction (libm sincosf was ~2x100 instr).
// All wave-uniform constants land in SGPRs via v_readlane.

namespace {
constexpr int kB = 4, kH = 32, kW = 32, kCIN = 3, kCOUT = 4;
constexpr int kFX = 30, kFY = 30;
}

template <int CTRL>
__device__ __forceinline__ float dpp_perm(float v) {
    return __int_as_float(
        __builtin_amdgcn_mov_dpp(__float_as_int(v), CTRL, 0xF, 0xF, true));
}
__device__ __forceinline__ float rdlane(float v, int l) {
    return __int_as_float(__builtin_amdgcn_readlane(__float_as_int(v), l));
}
__device__ __forceinline__ float sin_rev(float x) {
    float r; asm("v_sin_f32 %0, %1" : "=v"(r) : "v"(x)); return r;
}
__device__ __forceinline__ float cos_rev(float x) {
    float r; asm("v_cos_f32 %0, %1" : "=v"(r) : "v"(x)); return r;
}

// ---- gate macros (operate on re[8], im[8]) ------------------------------
// CRZ, lane ctrl (mask CB), register target bit TBIT.
#define CRZ_LR(CB, TBIT, K) do {                                           \
    const bool ctl = (lane & (CB)) != 0;                                   \
    const float ce = ctl ? gc[K] : 1.0f;                                   \
    const float se = ctl ? gs[K] : 0.0f;                                   \
    _Pragma("unroll")                                                      \
    for (int r = 0; r < 8; ++r) {                                          \
        const float sg = (r & (TBIT)) ? -se : se;                          \
        const float nr = ce * re[r] + sg * im[r];                          \
        const float ni = ce * im[r] - sg * re[r];                          \
        re[r] = nr; im[r] = ni;                                            \
    }                                                                      \
} while (0)

// CRX (real rotation), lane ctrl, register target bit.
#define CRX_LR(CB, TBIT, K) do {                                           \
    const bool ctl = (lane & (CB)) != 0;                                   \
    const float ce = ctl ? gc[K] : 1.0f;                                   \
    const float se = ctl ? gs[K] : 0.0f;                                   \
    _Pragma("unroll")                                                      \
    for (int r = 0; r < 8; ++r) if (!(r & (TBIT))) {                       \
        const int r2 = r | (TBIT);                                         \
        const float ar = re[r], ai = im[r], br = re[r2], bi = im[r2];      \
        re[r]  = ce * ar - se * br;  im[r]  = ce * ai - se * bi;           \
        re[r2] = se * ar + ce * br;  im[r2] = se * ai + ce * bi;           \
    }                                                                      \
} while (0)

// CRZ, register ctrl bit, register target bit.
#define CRZ_RR(CBIT, TBIT, K) do {                                         \
    const float ce = gc[K], se = gs[K];                                    \
    _Pragma("unroll")                                                      \
    for (int r = 0; r < 8; ++r) if (r & (CBIT)) {                          \
        const float sg = (r & (TBIT)) ? -se : se;                          \
        const float nr = ce * re[r] + sg * im[r];                          \
        const float ni = ce * im[r] - sg * re[r];                          \
        re[r] = nr; im[r] = ni;                                            \
    }                                                                      \
} while (0)

// CRX, register ctrl bit, register target bit.
#define CRX_RR(CBIT, TBIT, K) do {                                         \
    const float ce = gc[K], se = gs[K];                                    \
    _Pragma("unroll")                                                      \
    for (int r = 0; r < 8; ++r) if ((r & (CBIT)) && !(r & (TBIT))) {       \
        const int r2 = r | (TBIT);                                         \
        const float ar = re[r], ai = im[r], br = re[r2], bi = im[r2];      \
        re[r]  = ce * ar - se * br;  im[r]  = ce * ai - se * bi;           \
        re[r2] = se * ar + ce * br;  im[r2] = se * ai + ce * bi;           \
    }                                                                      \
} while (0)

// CRZ, lane ctrl, lane target bit.
#define CRZ_LL(CB, TB, K) do {                                             \
    const bool ctl = (lane & (CB)) != 0;                                   \
    const float ce  = ctl ? gc[K] : 1.0f;                                  \
    const float se0 = ctl ? gs[K] : 0.0f;                                  \
    const float se  = (lane & (TB)) ? -se0 : se0;                          \
    _Pragma("unroll")                                                      \
    for (int r = 0; r < 8; ++r) {                                          \
        const float nr = ce * re[r] + se * im[r];                          \
        const float ni = ce * im[r] - se * re[r];                          \
        re[r] = nr; im[r] = ni;                                            \
    }                                                                      \
} while (0)

// CRX, lane ctrl, lane target bit (partner via DPP quad_perm).
#define CRX_LL_DPP(CB, TB, DPPC, K) do {                                   \
    const bool ctl = (lane & (CB)) != 0;                                   \
    const float ce  = ctl ? gc[K] : 1.0f;                                  \
    const float se0 = ctl ? gs[K] : 0.0f;                                  \
    const float se  = (lane & (TB)) ? se0 : -se0;                          \
    _Pragma("unroll")                                                      \
    for (int r = 0; r < 8; ++r) {                                          \
        const float pr  = dpp_perm<DPPC>(re[r]);                           \
        const float pim = dpp_perm<DPPC>(im[r]);                           \
        re[r] = ce * re[r] + se * pr;                                      \
        im[r] = ce * im[r] + se * pim;                                     \
    }                                                                      \
} while (0)

__global__ __launch_bounds__(256) void quanv9q_kernel(
    const float* __restrict__ x, const float* __restrict__ qp,
    float* __restrict__ out)
{
    const int lane = threadIdx.x & 63;
    const int wave = (blockIdx.x << 2) + (threadIdx.x >> 6);

    // ---- fused border zeroing (out poisoned 0xAA each call): first 64 blocks
    {
        const int t = (blockIdx.x << 8) + threadIdx.x;
        if (t < kB * kH * kW * kCOUT) {
            const int w = (t >> 2) & 31, h = (t >> 7) & 31;
            if (h == 0 || h == 31 || w == 0 || w == 31) out[t] = 0.0f;
        }
    }

    const int co  = wave & 3;
    const int p   = wave >> 2;
    const int b   = p / (kFX * kFY);
    const int rem = p - b * (kFX * kFY);
    const int oy  = rem / kFY;
    const int ox  = rem - oy * kFY;

    // ---- trig (branchless; lanes >= needed just duplicate lane 0's work)
    // patch: theta = pi*v - pi/2 rad -> rev = 0.5*v - 0.25, in [-0.25, 0.25]
    const int li = lane < 9 ? lane : 0;
    const int di = li / 3, dj = li - di * 3;
    const float* px = x + (((b * kH + (oy + di)) * kW + (ox + dj)) * kCIN);
    const float v = (px[0] + px[1] + px[2]) * (1.0f / 3.0f);
    const float prev_ = 0.5f * v - 0.25f;
    const float myc = cos_rev(prev_), mys = sin_rev(prev_);
    // gate: theta = qp/2 rad -> rev = qp/(4*pi), in [-0.25, 0.25]
    const int gi = lane < 16 ? lane : 0;
    const float ga = qp[co * 16 + gi] * 0.07957747154594767f;
    const float mgc = cos_rev(ga), mgs = sin_rev(ga);

    // wave-uniform constants -> SGPRs
    float cq[9], sq[9];
    #pragma unroll
    for (int q = 0; q < 9; ++q) { cq[q] = rdlane(myc, q); sq[q] = rdlane(mys, q); }
    float gc[16], gs[16];
    #pragma unroll
    for (int k = 0; k < 16; ++k) { gc[k] = rdlane(mgc, k); gs[k] = rdlane(mgs, k); }

    // ---- real initial product state
    float pm = 1.0f;
    pm *= (lane & 1)  ? sq[7] : cq[7];
    pm *= (lane & 2)  ? sq[6] : cq[6];
    pm *= (lane & 4)  ? sq[8] : cq[8];
    pm *= (lane & 8)  ? sq[5] : cq[5];
    pm *= (lane & 16) ? sq[3] : cq[3];
    pm *= (lane & 32) ? sq[1] : cq[1];

    float re[8], im[8];
    {
        const float a0 = pm * cq[0], a1 = pm * sq[0];                 // q0 (bit2)
        const float b00 = a0 * cq[2], b01 = a0 * sq[2];               // q2 (bit1)
        const float b10 = a1 * cq[2], b11 = a1 * sq[2];
        re[0] = b00 * cq[4]; re[1] = b00 * sq[4];                     // q4 (bit0)
        re[2] = b01 * cq[4]; re[3] = b01 * sq[4];
        re[4] = b10 * cq[4]; re[5] = b10 * sq[4];
        re[6] = b11 * cq[4]; re[7] = b11 * sq[4];
    }

    // ---- gates; lane masks: q1=32 q3=16 q5=8 q8=4 q6=2 q7=1
    // gate (1,0) CRZ specialized for im == 0: re'=ce*re, im'=-sg*re
    {
        const bool ctl = (lane & 32) != 0;
        const float ce = ctl ? gc[0] : 1.0f;
        const float se = ctl ? gs[0] : 0.0f;
        #pragma unroll
        for (int r = 0; r < 8; ++r) {
            const float sg = (r & 4) ? -se : se;
            im[r] = -sg * re[r];
            re[r] = ce * re[r];
        }
    }
    CRX_LR(32, 4, 1);                              // (1,0)
    CRZ_LR(16, 2, 2);   CRX_LR(16, 2, 3);          // (3,2)
    CRZ_RR(2, 4, 4);    CRX_RR(2, 4, 5);           // (2,0)
    CRZ_LL(4, 1, 6);    CRX_LL_DPP(4, 1, 0xB1, 7); // (8,7) xor1
    CRZ_LR(8, 1, 8);    CRX_LR(8, 1, 9);           // (5,4)
    CRZ_LL(1, 2, 10);   CRX_LL_DPP(1, 2, 0x4E, 11);// (7,6) xor2
    CRZ_LR(2, 1, 12);   CRX_LR(2, 1, 13);          // (6,4)
    CRZ_RR(1, 4, 14);   CRX_RR(1, 4, 15);          // (4,0)

    // ---- p0 = sum |amp|^2 over q0=0 (regs 0..3), all lanes
    float ssum = 0.0f;
    #pragma unroll
    for (int r = 0; r < 4; ++r) ssum += re[r] * re[r] + im[r] * im[r];
    #pragma unroll
    for (int off = 32; off > 0; off >>= 1) ssum += __shfl_xor(ssum, off, 64);

    if (lane == 0)
        out[((b * kH + (oy + 1)) * kW + (ox + 1)) * kCOUT + co] = ssum;
}

extern "C" void kernel_launch(void* const* d_in, const int* in_sizes, int n_in,
                              void* d_out, int out_size, void* d_ws, size_t ws_size,
                              hipStream_t stream) {
    const float* x  = (const float*)d_in[0];   // (4,32,32,3) f32
    const float* qp = (const float*)d_in[1];   // (4,16) f32
    float* out = (float*)d_out;                // (4,32,32,4) f32

    const int total_waves = kB * kFX * kFY * kCOUT;                 // 14400
    const int threads = 256;                                        // 4 waves/block
    const int blocks = total_waves * 64 / threads;                  // 3600 exact
    quanv9q_kernel<<<blocks, threads, 0, stream>>>(x, qp, out);
}